// Round 1
// baseline (300.501 us; speedup 1.0000x reference)
//
#include <hip/hip_runtime.h>

typedef _Float16 f16;
typedef __attribute__((ext_vector_type(4))) _Float16 f16x4;
typedef __attribute__((ext_vector_type(8))) _Float16 f16x8;
typedef __attribute__((ext_vector_type(4))) float f32x4;

#define B_ 4
#define N_ 2048
#define D_ 1024

// ---------------------------------------------------------------- cast fp32->fp16 + rowsum zeroing
__global__ __launch_bounds__(256) void k_cast_all(const float4* __restrict__ x,
                                                  const float4* __restrict__ wq,
                                                  const float4* __restrict__ wk,
                                                  const float4* __restrict__ wv,
                                                  f16x4* __restrict__ xo,
                                                  f16x4* __restrict__ wqo,
                                                  f16x4* __restrict__ wko,
                                                  f16x4* __restrict__ wvo,
                                                  float* __restrict__ rowsum) {
  int b = blockIdx.x;
  if (b >= 11264) {                      // 32 blocks zero the 8192-float rowsum
    rowsum[(b - 11264) * 256 + threadIdx.x] = 0.f;
    return;
  }
  const float4* in;
  f16x4* out;
  int idx;
  if (b < 8192)       { in = x;  out = xo;  idx = b * 256 + threadIdx.x; }
  else if (b < 9216)  { in = wq; out = wqo; idx = (b - 8192) * 256 + threadIdx.x; }
  else if (b < 10240) { in = wk; out = wko; idx = (b - 9216) * 256 + threadIdx.x; }
  else                { in = wv; out = wvo; idx = (b - 10240) * 256 + threadIdx.x; }
  float4 v = in[idx];
  f16x4 o = { (_Float16)v.x, (_Float16)v.y, (_Float16)v.z, (_Float16)v.w };
  out[idx] = o;
}

// ---------------------------------------------------------------- staging
// K-tile rows are 64 B (BK=32 f16); 16B chunks XOR-swizzled by (row&3) on the
// GLOBAL source (linear LDS dest, per global_load_lds constraint); reads apply
// the same XOR -> both-sides involution.
__device__ __forceinline__ void stage32(const char* g0, int ldBytes, int kByte,
                                        char* slot, int tid, int nrounds) {
#pragma unroll
  for (int r = 0; r < 2; ++r) {
    if (r < nrounds) {
      int lin = r * 8192 + tid * 16;
      int row = lin >> 6;
      int lch = ((lin >> 4) & 3) ^ (row & 3);
      const char* g = g0 + (long)row * ldBytes + kByte + lch * 16;
      char* l = slot + r * 8192 + ((tid >> 6) << 10);   // wave-uniform base; HW adds lane*16
      __builtin_amdgcn_global_load_lds(
          (const __attribute__((address_space(1))) unsigned int*)g,
          (__attribute__((address_space(3))) unsigned int*)l, 16, 0, 0);
    }
  }
}

// ---------------------------------------------------------------- pipelined NT GEMM, 256x256 tile
// BK=32, 8 waves (2M x 4N), per-wave 128x64, triple-buffered 32 KB slots (96 KB).
// Schedule: compute tile t from slot t%3 while staging tile t+2 into slot (t+2)%3
// (its old contents, tile t-1, were last read in group t-1 -> race-free).
// Boundary: vmcnt(4) = exactly tile t+1's in-flight loads; never 0 except last tile.
__device__ __forceinline__ void gemm_pipe256(const char* gA, int ldaB,
                                             const char* gB, int ldbB,
                                             int nK, char* lds, f32x4 acc[8][4]) {
  const int tid = threadIdx.x;
  const int lane = tid & 63, wave = tid >> 6;
  const int wm = wave >> 2, wn = wave & 3;
  const int quad = lane >> 4, l16 = lane & 15;
  stage32(gA, ldaB, 0, lds, tid, 2);
  stage32(gB, ldbB, 0, lds + 16384, tid, 2);
  stage32(gA, ldaB, 64, lds + 32768, tid, 2);
  stage32(gB, ldbB, 64, lds + 49152, tid, 2);
  int cs = 0;
  for (int t = 0; t < nK; ++t) {
    char* sA = lds + cs * 32768;
    char* sB = sA + 16384;
    int ns = cs - 1; if (ns < 0) ns = 2;        // (t+2)%3
    char* nA = lds + ns * 32768;
    const bool st = (t + 2 < nK);
    const int kB = (t + 2) << 6;
    if (t + 1 < nK) asm volatile("s_waitcnt vmcnt(4)" ::: "memory");
    else            asm volatile("s_waitcnt vmcnt(0)" ::: "memory");
    __builtin_amdgcn_s_barrier();
    // phase 0: rows 0..63 of this wave's 128, all 4 col-frags
    f16x8 af[4], bf[4];
#pragma unroll
    for (int i = 0; i < 4; ++i) {
      int rA = wm * 128 + i * 16 + l16;
      af[i] = *(const f16x8*)(sA + rA * 64 + ((quad ^ (rA & 3)) << 4));
    }
#pragma unroll
    for (int j = 0; j < 4; ++j) {
      int rB = wn * 64 + j * 16 + l16;
      bf[j] = *(const f16x8*)(sB + rB * 64 + ((quad ^ (rB & 3)) << 4));
    }
    if (st) stage32(gA, ldaB, kB, nA, tid, 2);
    __builtin_amdgcn_s_barrier();
    __builtin_amdgcn_s_setprio(1);
#pragma unroll
    for (int i = 0; i < 4; ++i)
#pragma unroll
      for (int j = 0; j < 4; ++j)
        acc[i][j] = __builtin_amdgcn_mfma_f32_16x16x32_f16(af[i], bf[j], acc[i][j], 0, 0, 0);
    __builtin_amdgcn_s_setprio(0);
    __builtin_amdgcn_s_barrier();
    // phase 1: rows 64..127 (bf reused)
#pragma unroll
    for (int i = 0; i < 4; ++i) {
      int rA = wm * 128 + (i + 4) * 16 + l16;
      af[i] = *(const f16x8*)(sA + rA * 64 + ((quad ^ (rA & 3)) << 4));
    }
    if (st) stage32(gB, ldbB, kB, nA + 16384, tid, 2);
    __builtin_amdgcn_s_barrier();
    __builtin_amdgcn_s_setprio(1);
#pragma unroll
    for (int i = 0; i < 4; ++i)
#pragma unroll
      for (int j = 0; j < 4; ++j)
        acc[i + 4][j] = __builtin_amdgcn_mfma_f32_16x16x32_f16(af[i], bf[j], acc[i + 4][j], 0, 0, 0);
    __builtin_amdgcn_s_setprio(0);
    cs = (cs == 2) ? 0 : cs + 1;
  }
  __builtin_amdgcn_s_barrier();   // all loads drained (vmcnt(0) at last tile) + reads done
}

// ---------------------------------------------------------------- pipelined NT GEMM, 256x128 tile
// 8 waves (4M x 2N), per-wave 64x64, triple-buffered 24 KB slots (72 KB). vmcnt(3).
__device__ __forceinline__ void gemm_pipe128(const char* gA, int ldaB,
                                             const char* gB, int ldbB,
                                             int nK, char* lds, f32x4 acc[4][4]) {
  const int tid = threadIdx.x;
  const int lane = tid & 63, wave = tid >> 6;
  const int wm = wave >> 1, wn = wave & 1;
  const int quad = lane >> 4, l16 = lane & 15;
  stage32(gA, ldaB, 0, lds, tid, 2);
  stage32(gB, ldbB, 0, lds + 16384, tid, 1);
  stage32(gA, ldaB, 64, lds + 24576, tid, 2);
  stage32(gB, ldbB, 64, lds + 40960, tid, 1);
  int cs = 0;
  for (int t = 0; t < nK; ++t) {
    char* sA = lds + cs * 24576;
    char* sB = sA + 16384;
    int ns = cs - 1; if (ns < 0) ns = 2;
    char* nA = lds + ns * 24576;
    const bool st = (t + 2 < nK);
    const int kB = (t + 2) << 6;
    if (t + 1 < nK) asm volatile("s_waitcnt vmcnt(3)" ::: "memory");
    else            asm volatile("s_waitcnt vmcnt(0)" ::: "memory");
    __builtin_amdgcn_s_barrier();
    f16x8 af[4], bf[4];
#pragma unroll
    for (int i = 0; i < 4; ++i) {
      int rA = wm * 64 + i * 16 + l16;
      af[i] = *(const f16x8*)(sA + rA * 64 + ((quad ^ (rA & 3)) << 4));
    }
#pragma unroll
    for (int j = 0; j < 4; ++j) {
      int rB = wn * 64 + j * 16 + l16;
      bf[j] = *(const f16x8*)(sB + rB * 64 + ((quad ^ (rB & 3)) << 4));
    }
    if (st) { stage32(gA, ldaB, kB, nA, tid, 2); stage32(gB, ldbB, kB, nA + 16384, tid, 1); }
    __builtin_amdgcn_s_barrier();
    __builtin_amdgcn_s_setprio(1);
#pragma unroll
    for (int i = 0; i < 4; ++i)
#pragma unroll
      for (int j = 0; j < 4; ++j)
        acc[i][j] = __builtin_amdgcn_mfma_f32_16x16x32_f16(af[i], bf[j], acc[i][j], 0, 0, 0);
    __builtin_amdgcn_s_setprio(0);
    cs = (cs == 2) ? 0 : cs + 1;
  }
  __builtin_amdgcn_s_barrier();
}

// ---------------------------------------------------------------- fused QKV projection (+V transpose)
// Wide GEMM [8192, 3072]: col-tile 0..11 selects Wq/Wk/Wv. 384 blocks.
__global__ __launch_bounds__(512, 2) void k_qkv(const f16* __restrict__ X,
                                                const f16* __restrict__ Wq,
                                                const f16* __restrict__ Wk,
                                                const f16* __restrict__ Wv,
                                                const float* __restrict__ bq,
                                                const float* __restrict__ bk,
                                                const float* __restrict__ bv,
                                                f16* __restrict__ Q, f16* __restrict__ Ko,
                                                f16* __restrict__ Vt) {
  __shared__ __align__(16) char lds[98304];
  int fid = blockIdx.x;
  int xcd = fid & 7, k = fid >> 3;          // k in [0,48)
  int rowt = xcd * 4 + (k & 3);             // XCD band: 4 row-tiles, X panel reuse in L2
  int colt = k >> 2;                        // 0..11
  int tm = rowt * 256;
  int w = colt >> 2;                        // 0:Q 1:K 2:V
  int tn = (colt & 3) * 256;
  const f16* Wsel = (w == 0) ? Wq : (w == 1) ? Wk : Wv;
  f32x4 acc[8][4];
#pragma unroll
  for (int i = 0; i < 8; ++i)
#pragma unroll
    for (int j = 0; j < 4; ++j) acc[i][j] = (f32x4){0.f, 0.f, 0.f, 0.f};
  gemm_pipe256((const char*)(X + (long)tm * D_), D_ * 2,
               (const char*)(Wsel + (long)tn * D_), D_ * 2, D_ / 32, lds, acc);
  const int tid = threadIdx.x;
  const int lane = tid & 63, wave = tid >> 6;
  const int wm = wave >> 2, wn = wave & 3;
  const int quad = lane >> 4, l16 = lane & 15;
  if (w < 2) {
    const float* bias = w ? bk : bq;
    f16* out = w ? Ko : Q;
#pragma unroll
    for (int j = 0; j < 4; ++j) {
      int col = tn + wn * 64 + j * 16 + l16;
      float bb = bias[col];
#pragma unroll
      for (int i = 0; i < 8; ++i) {
        int rbase = tm + wm * 128 + i * 16 + quad * 4;
#pragma unroll
        for (int r = 0; r < 4; ++r)
          out[(long)(rbase + r) * D_ + col] = (_Float16)(acc[i][j][r] + bb);
      }
    }
  } else {
    // V: transpose through LDS in 2 feature-passes of 128 (256x264 won't fit)
    int bidx = tm >> 11, ntok = tm & 2047;
    f16* VtB = Vt + (long)bidx * D_ * N_ + ntok;
    f16* ldsT = (f16*)lds;                  // 128 x 264 f16
    for (int pass = 0; pass < 2; ++pass) {
      __builtin_amdgcn_s_barrier();
      if ((wn >> 1) == pass) {
        int wnl = wn & 1;
#pragma unroll
        for (int j = 0; j < 4; ++j) {
          int cl = wnl * 64 + j * 16 + l16;             // local feature 0..127
          float bb = bv[tn + pass * 128 + cl];
#pragma unroll
          for (int i = 0; i < 8; ++i) {
            int rl = wm * 128 + i * 16 + quad * 4;      // local token 0..255
            f16x4 p = { (_Float16)(acc[i][j][0] + bb), (_Float16)(acc[i][j][1] + bb),
                        (_Float16)(acc[i][j][2] + bb), (_Float16)(acc[i][j][3] + bb) };
            *(f16x4*)(ldsT + cl * 264 + rl) = p;
          }
        }
      }
      __builtin_amdgcn_s_barrier();
#pragma unroll
      for (int p = 0; p < 8; ++p) {
        int f = p * 16 + (tid >> 5);
        int c = tid & 31;
        f16x8 v = *(const f16x8*)(ldsT + f * 264 + c * 8);
        *(f16x8*)(VtB + (long)(tn + pass * 128 + f) * N_ + c * 8) = v;
      }
    }
  }
}

// ---------------------------------------------------------------- scores: P' = exp(QK^T*delta)
// 256x256 tile, 256 blocks (exactly 1/CU). Coalesced f16 stores via 2-pass LDS bounce.
__global__ __launch_bounds__(512, 2) void k_scores(const f16* __restrict__ Qf,
                                                   const f16* __restrict__ Kf,
                                                   f16* __restrict__ S,
                                                   float* __restrict__ rowsum) {
  __shared__ __align__(16) char lds[98304];
  int fid = blockIdx.x;
  int xcd = fid & 7, k = fid >> 3;
  int lin = xcd * 32 + k;
  int b = lin >> 6;
  int t = lin & 63;
  int rowt = t & 7, colt = t >> 3;
  int tm = rowt * 256, tn = colt * 256;
  f32x4 acc[8][4];
#pragma unroll
  for (int i = 0; i < 8; ++i)
#pragma unroll
    for (int j = 0; j < 4; ++j) acc[i][j] = (f32x4){0.f, 0.f, 0.f, 0.f};
  gemm_pipe256((const char*)(Qf + (long)b * N_ * D_ + (long)tm * D_), D_ * 2,
               (const char*)(Kf + (long)b * N_ * D_ + (long)tn * D_), D_ * 2,
               D_ / 32, lds, acc);
  const int tid = threadIdx.x;
  const int lane = tid & 63, wave = tid >> 6;
  const int wm = wave >> 2, wn = wave & 3;
  const int quad = lane >> 4, l16 = lane & 15;
  f16* Sb = S + (long)b * N_ * N_;
  const float delta = 0.03125f;             // 1/sqrt(1024); exp <= ~e^6, f16-safe
  f16* ldsS = (f16*)lds;                    // 256 x 136 f16 per pass
  float rsum[8][4];
#pragma unroll
  for (int i = 0; i < 8; ++i)
#pragma unroll
    for (int r = 0; r < 4; ++r) rsum[i][r] = 0.f;
  for (int pass = 0; pass < 2; ++pass) {
    __builtin_amdgcn_s_barrier();
    if ((wn >> 1) == pass) {                // each wave's 64 cols live in one pass
      int wnl = wn & 1;
#pragma unroll
      for (int j = 0; j < 4; ++j) {
        int col = wnl * 64 + j * 16 + l16;
#pragma unroll
        for (int i = 0; i < 8; ++i) {
          int rbase = wm * 128 + i * 16 + quad * 4;
#pragma unroll
          for (int r = 0; r < 4; ++r) {
            float e = __expf(acc[i][j][r] * delta);
            rsum[i][r] += e;
            ldsS[(rbase + r) * 136 + col] = (_Float16)e;
          }
        }
      }
    }
    __builtin_amdgcn_s_barrier();
    // coalesced stores: 256 rows x 128 f16 per pass
#pragma unroll
    for (int p = 0; p < 8; ++p) {
      int row = p * 32 + (tid >> 4);
      int c = tid & 15;
      f16x8 v = *(const f16x8*)(ldsS + row * 136 + c * 8);
      *(f16x8*)(Sb + (long)(tm + row) * N_ + tn + pass * 128 + c * 8) = v;
    }
  }
#pragma unroll
  for (int m = 1; m < 16; m <<= 1)
#pragma unroll
    for (int i = 0; i < 8; ++i)
#pragma unroll
      for (int r = 0; r < 4; ++r) rsum[i][r] += __shfl_xor(rsum[i][r], m);
  if (l16 == 0) {
    float* rs = rowsum + (long)b * N_ + tm;
#pragma unroll
    for (int i = 0; i < 8; ++i)
#pragma unroll
      for (int r = 0; r < 4; ++r)
        atomicAdd(rs + wm * 128 + i * 16 + quad * 4 + r, rsum[i][r]);
  }
}

// ---------------------------------------------------------------- O = (P' V)/rowsum * gamma + x
// 256x128 tile so grid = 256 blocks (256x256 would leave half the CUs idle at 128).
__global__ __launch_bounds__(512, 2) void k_out(const f16* __restrict__ P,
                                                const f16* __restrict__ Vt,
                                                const f16* __restrict__ xf,
                                                const float* __restrict__ gamma,
                                                const float* __restrict__ rowsum,
                                                float* __restrict__ out) {
  __shared__ __align__(16) char lds[73728];
  int fid = blockIdx.x;
  int xcd = fid & 7, kq = fid >> 3;
  int lin = xcd * 32 + kq;
  int b = lin >> 6;
  int t = lin & 63;
  int rowt = t >> 3, colt = t & 7;          // colt fast: P row-panel reused across 8 blocks
  int tm = rowt * 256, tn = colt * 128;
  f32x4 acc[4][4];
#pragma unroll
  for (int i = 0; i < 4; ++i)
#pragma unroll
    for (int j = 0; j < 4; ++j) acc[i][j] = (f32x4){0.f, 0.f, 0.f, 0.f};
  gemm_pipe128((const char*)(P + (long)b * N_ * N_ + (long)tm * N_), N_ * 2,
               (const char*)(Vt + (long)b * D_ * N_ + (long)tn * N_), N_ * 2,
               N_ / 32, lds, acc);
  const int tid = threadIdx.x;
  const int lane = tid & 63, wave = tid >> 6;
  const int wm = wave >> 1, wn = wave & 1;
  const int quad = lane >> 4, l16 = lane & 15;
  float g = gamma[0];
  float inv[4][4];
#pragma unroll
  for (int i = 0; i < 4; ++i)
#pragma unroll
    for (int r = 0; r < 4; ++r)
      inv[i][r] = g / rowsum[(long)b * N_ + tm + wm * 64 + i * 16 + quad * 4 + r];
#pragma unroll
  for (int j = 0; j < 4; ++j) {
    int col = tn + wn * 64 + j * 16 + l16;
#pragma unroll
    for (int i = 0; i < 4; ++i) {
      int rbase = tm + wm * 64 + i * 16 + quad * 4;
#pragma unroll
      for (int r = 0; r < 4; ++r) {
        long idx = (long)b * N_ * D_ + (long)(rbase + r) * D_ + col;
        out[idx] = acc[i][j][r] * inv[i][r] + (float)xf[idx];
      }
    }
  }
}

// ---------------------------------------------------------------- launch
extern "C" void kernel_launch(void* const* d_in, const int* in_sizes, int n_in,
                              void* d_out, int out_size, void* d_ws, size_t ws_size,
                              hipStream_t stream) {
  const float* x  = (const float*)d_in[0];
  const float* Wq = (const float*)d_in[1];
  const float* bq = (const float*)d_in[2];
  const float* Wk = (const float*)d_in[3];
  const float* bk = (const float*)d_in[4];
  const float* Wv = (const float*)d_in[5];
  const float* bv = (const float*)d_in[6];
  const float* gamma = (const float*)d_in[7];
  float* out = (float*)d_out;
  char* ws = (char*)d_ws;

  // ws layout: Xb stays ALIVE through k_out (x re-read as f16).
  // S overlays only the dead W buffers. Peak 96 MB (+32 KB rowsum).
  f16* Qb  = (f16*)(ws);                      // 0..16 MB
  f16* Kb  = (f16*)(ws + (16u << 20));        // 16..32 MB
  f16* Vt  = (f16*)(ws + (32u << 20));        // 32..48 MB (written directly by k_qkv)
  f16* Xb  = (f16*)(ws + (48u << 20));        // 48..64 MB (alive through k_out)
  f16* Wqb = (f16*)(ws + (64u << 20));        // 64..66 MB (dead after k_qkv)
  f16* Wkb = (f16*)(ws + (66u << 20));        // 66..68 MB
  f16* Wvb = (f16*)(ws + (68u << 20));        // 68..70 MB
  f16* S   = (f16*)(ws + (64u << 20));        // 64..96 MB, overlays dead W's
  float* rowsum = (float*)(ws + (96u << 20)); // 32 KB

  k_cast_all<<<11296, 256, 0, stream>>>((const float4*)x, (const float4*)Wq,
                                        (const float4*)Wk, (const float4*)Wv,
                                        (f16x4*)Xb, (f16x4*)Wqb, (f16x4*)Wkb, (f16x4*)Wvb,
                                        rowsum);
  k_qkv<<<384, 512, 0, stream>>>(Xb, Wqb, Wkb, Wvb, bq, bk, bv, Qb, Kb, Vt);
  k_scores<<<256, 512, 0, stream>>>(Qb, Kb, S, rowsum);
  k_out<<<256, 512, 0, stream>>>(S, Vt, Xb, gamma, rowsum, out);
}

// Round 2
// 250.141 us; speedup vs baseline: 1.2013x; 1.2013x over previous
//
#include <hip/hip_runtime.h>

typedef _Float16 f16;
typedef __attribute__((ext_vector_type(4))) _Float16 f16x4;
typedef __attribute__((ext_vector_type(8))) _Float16 f16x8;
typedef __attribute__((ext_vector_type(4))) float f32x4;

#define B_ 4
#define N_ 2048
#define D_ 1024

#define FENCE asm volatile("" ::: "memory")

// ---------------------------------------------------------------- cast fp32->fp16 + rowsum zeroing
__global__ __launch_bounds__(256) void k_cast_all(const float4* __restrict__ x,
                                                  const float4* __restrict__ wq,
                                                  const float4* __restrict__ wk,
                                                  const float4* __restrict__ wv,
                                                  f16x4* __restrict__ xo,
                                                  f16x4* __restrict__ wqo,
                                                  f16x4* __restrict__ wko,
                                                  f16x4* __restrict__ wvo,
                                                  float* __restrict__ rowsum) {
  int b = blockIdx.x;
  if (b >= 11264) {                      // 32 blocks zero the 8192-float rowsum
    rowsum[(b - 11264) * 256 + threadIdx.x] = 0.f;
    return;
  }
  const float4* in;
  f16x4* out;
  int idx;
  if (b < 8192)       { in = x;  out = xo;  idx = b * 256 + threadIdx.x; }
  else if (b < 9216)  { in = wq; out = wqo; idx = (b - 8192) * 256 + threadIdx.x; }
  else if (b < 10240) { in = wk; out = wko; idx = (b - 9216) * 256 + threadIdx.x; }
  else                { in = wv; out = wvo; idx = (b - 10240) * 256 + threadIdx.x; }
  float4 v = in[idx];
  f16x4 o = { (_Float16)v.x, (_Float16)v.y, (_Float16)v.z, (_Float16)v.w };
  out[idx] = o;
}

// ---------------------------------------------------------------- staging (PROVEN-CLEAN geometry)
// Half-tile = 128 rows x 128 B (BK=64 f16). 16B chunks XOR-swizzled by (row&7)
// on the GLOBAL source (LDS dest stays linear per global_load_lds constraint);
// reads apply the same XOR -> both-sides involution. 2 loads/thread.
__device__ __forceinline__ void stage_half(const char* g0, int ldB, int kByte,
                                           char* slot, int tid) {
#pragma unroll
  for (int r = 0; r < 2; ++r) {
    int lin = r * 8192 + tid * 16;
    int row = lin >> 7;
    int lch = ((lin >> 4) & 7) ^ (row & 7);
    const char* g = g0 + (long)row * ldB + kByte + lch * 16;
    char* l = slot + r * 8192 + ((tid >> 6) << 10);   // wave-uniform base; HW adds lane*16
    __builtin_amdgcn_global_load_lds(
        (const __attribute__((address_space(1))) unsigned int*)g,
        (__attribute__((address_space(3))) unsigned int*)l, 16, 0, 0);
  }
}

// ---------------------------------------------------------------- 256x256 pipelined NT GEMM
// 8 waves; per-wave output: rows {wm*64..+63} in EACH A-half, cols {wn*32..+31}
// in EACH B-half -> every wave works in every quadrant-phase.
// dbuf LDS 128 KB. 4 phases/K-tile, quadrant (Ah,Bh) = (0,0),(1,0),(0,1),(1,1).
// Issue order of tile t+1 halves: A0(ph0), B0(ph1), A1(ph2), B1(ph3).
// Waits: vmcnt(4) at ph0/1/2 (tail: 4/2/0) -> queue NEVER drains mid-loop.
__device__ __forceinline__ void gemm256(const char* gA, int ldaB,
                                        const char* gB, int ldbB,
                                        int nK, char* lds, f32x4 acc[2][4][2][2]) {
  const int tid = threadIdx.x;
  const int lane = tid & 63;
  const int wave = tid >> 6;
  const int wm = wave >> 2, wn = wave & 3;
  const int quad = lane >> 4, l16 = lane & 15;
  const int l7 = l16 & 7;
  const char* gA1 = gA + (long)128 * ldaB;
  const char* gB1 = gB + (long)128 * ldbB;
  char* Abuf = lds;            // 2 x 32 KB (half h at +h*16384)
  char* Bbuf = lds + 65536;    // 2 x 32 KB
  stage_half(gA,  ldaB, 0, Abuf, tid);
  stage_half(gB,  ldbB, 0, Bbuf, tid);
  stage_half(gA1, ldaB, 0, Abuf + 16384, tid);
  stage_half(gB1, ldbB, 0, Bbuf + 16384, tid);
  for (int t = 0; t < nK; ++t) {
    const int c = t & 1;
    char* Ac = Abuf + c * 32768;
    char* Bc = Bbuf + c * 32768;
    char* An = Abuf + (c ^ 1) * 32768;
    char* Bn = Bbuf + (c ^ 1) * 32768;
    const bool st = (t + 1 < nK);
    const int kB = (t + 1) << 7;
    f16x8 bf[2][2];
#pragma unroll
    for (int ph = 0; ph < 4; ++ph) {
      const int Ah = ph & 1, Bh = ph >> 1;
      if (ph == 0)      { asm volatile("s_waitcnt vmcnt(4)" ::: "memory"); }
      else if (ph == 1) { if (st) asm volatile("s_waitcnt vmcnt(4)" ::: "memory");
                          else    asm volatile("s_waitcnt vmcnt(2)" ::: "memory"); }
      else if (ph == 2) { if (st) asm volatile("s_waitcnt vmcnt(4)" ::: "memory");
                          else    asm volatile("s_waitcnt vmcnt(0)" ::: "memory"); }
      __builtin_amdgcn_s_barrier();
      FENCE;
      f16x8 af[4][2];
      const char* Ab = Ac + Ah * 16384;
#pragma unroll
      for (int i = 0; i < 4; ++i) {
        int rA = wm * 64 + i * 16 + l16;
#pragma unroll
        for (int kk = 0; kk < 2; ++kk)
          af[i][kk] = *(const f16x8*)(Ab + rA * 128 + ((((kk << 2) | quad) ^ l7) << 4));
      }
      if (Ah == 0) {               // (re)load bf at ph0 (B0) and ph2 (B1)
        const char* Bb = Bc + Bh * 16384;
#pragma unroll
        for (int jn = 0; jn < 2; ++jn) {
          int rB = wn * 32 + jn * 16 + l16;
#pragma unroll
          for (int kk = 0; kk < 2; ++kk)
            bf[jn][kk] = *(const f16x8*)(Bb + rB * 128 + ((((kk << 2) | quad) ^ l7) << 4));
        }
      }
      if (st) {
        if (ph == 0)      stage_half(gA,  ldaB, kB, An, tid);
        else if (ph == 1) stage_half(gB,  ldbB, kB, Bn, tid);
        else if (ph == 2) stage_half(gA1, ldaB, kB, An + 16384, tid);
        else              stage_half(gB1, ldbB, kB, Bn + 16384, tid);
      }
      FENCE;
      __builtin_amdgcn_s_barrier();
      __builtin_amdgcn_s_setprio(1);
#pragma unroll
      for (int i = 0; i < 4; ++i)
#pragma unroll
        for (int jn = 0; jn < 2; ++jn)
#pragma unroll
          for (int kk = 0; kk < 2; ++kk)
            acc[Ah][i][Bh][jn] = __builtin_amdgcn_mfma_f32_16x16x32_f16(
                af[i][kk], bf[jn][kk], acc[Ah][i][Bh][jn], 0, 0, 0);
      __builtin_amdgcn_s_setprio(0);
    }
  }
  asm volatile("s_waitcnt vmcnt(0)" ::: "memory");
  __builtin_amdgcn_s_barrier();
  FENCE;
}

// ---------------------------------------------------------------- 256x128 pipelined NT GEMM
// 8 waves (4M x 2N), per-wave 64x64. TRIPLE-buffered 48 KB slots (144 KB total).
// Compute tile t from slot t%3 while staging tile t+2 into slot (t+2)%3.
// One vmcnt(6) per K-tile (= the full next tile stays in flight); drains only at tail.
__device__ __forceinline__ void gemm_tb(const char* gA, int ldaB,
                                        const char* gB, int ldbB,
                                        int nK, char* lds, f32x4 acc[4][4]) {
  const int tid = threadIdx.x;
  const int lane = tid & 63;
  const int wave = tid >> 6;
  const int wm = wave >> 1, wn = wave & 1;
  const int quad = lane >> 4, l16 = lane & 15;
  const int l7 = l16 & 7;
  const char* gA1 = gA + (long)128 * ldaB;
  // slot layout: [A 32 KB (256 rows) | B 16 KB (128 rows)]
  stage_half(gA,  ldaB, 0, lds, tid);
  stage_half(gA1, ldaB, 0, lds + 16384, tid);
  stage_half(gB,  ldbB, 0, lds + 32768, tid);
  stage_half(gA,  ldaB, 128, lds + 49152, tid);
  stage_half(gA1, ldaB, 128, lds + 49152 + 16384, tid);
  stage_half(gB,  ldbB, 128, lds + 49152 + 32768, tid);
  int cs = 0;
  for (int t = 0; t < nK; ++t) {
    char* Ac = lds + cs * 49152;
    char* Bc = Ac + 32768;
    int ns = cs + 2; if (ns >= 3) ns -= 3;
    char* An = lds + ns * 49152;
    const bool st = (t + 2 < nK);
    const int kB = (t + 2) << 7;
#pragma unroll
    for (int ph = 0; ph < 2; ++ph) {
      if (ph == 0) {
        if (t + 1 < nK) asm volatile("s_waitcnt vmcnt(6)" ::: "memory");
        else            asm volatile("s_waitcnt vmcnt(0)" ::: "memory");
      }
      __builtin_amdgcn_s_barrier();
      FENCE;
      f16x8 af[4], bf[4];
#pragma unroll
      for (int i = 0; i < 4; ++i) {
        int rA = wm * 64 + i * 16 + l16;
        af[i] = *(const f16x8*)(Ac + rA * 128 + ((((ph << 2) | quad) ^ l7) << 4));
      }
#pragma unroll
      for (int j = 0; j < 4; ++j) {
        int rB = wn * 64 + j * 16 + l16;
        bf[j] = *(const f16x8*)(Bc + rB * 128 + ((((ph << 2) | quad) ^ l7) << 4));
      }
      if (st) {
        if (ph == 0) { stage_half(gA,  ldaB, kB, An, tid);
                       stage_half(gA1, ldaB, kB, An + 16384, tid); }
        else         { stage_half(gB,  ldbB, kB, An + 32768, tid); }
      }
      FENCE;
      __builtin_amdgcn_s_barrier();
      __builtin_amdgcn_s_setprio(1);
#pragma unroll
      for (int i = 0; i < 4; ++i)
#pragma unroll
        for (int j = 0; j < 4; ++j)
          acc[i][j] = __builtin_amdgcn_mfma_f32_16x16x32_f16(af[i], bf[j], acc[i][j], 0, 0, 0);
      __builtin_amdgcn_s_setprio(0);
    }
    cs = cs + 1; if (cs == 3) cs = 0;
  }
  asm volatile("s_waitcnt vmcnt(0)" ::: "memory");
  __builtin_amdgcn_s_barrier();
  FENCE;
}

// ---------------------------------------------------------------- fused QKV projection (+V transpose)
// Wide GEMM [8192, 3072] in 256x128 tiles -> 768 blocks = exactly 3 full GPU rounds.
__global__ __launch_bounds__(512, 2) void k_qkv(const f16* __restrict__ X,
                                                const f16* __restrict__ Wq,
                                                const f16* __restrict__ Wk,
                                                const f16* __restrict__ Wv,
                                                const float* __restrict__ bq,
                                                const float* __restrict__ bk,
                                                const float* __restrict__ bv,
                                                f16* __restrict__ Q, f16* __restrict__ Ko,
                                                f16* __restrict__ Vt) {
  __shared__ __align__(16) char lds[147456];
  int fid = blockIdx.x;
  int xcd = fid & 7, k = fid >> 3;          // k in [0,96)
  int rowt = xcd * 4 + (k & 3);             // XCD band of 4 row-tiles: X panels L2-resident
  int colt = k >> 2;                        // 0..23
  int tm = rowt * 256;
  int w = colt >> 3;                        // 0:Q 1:K 2:V
  int tnl = (colt & 7) * 128;
  const f16* Wsel = (w == 0) ? Wq : (w == 1) ? Wk : Wv;
  f32x4 acc[4][4];
#pragma unroll
  for (int i = 0; i < 4; ++i)
#pragma unroll
    for (int j = 0; j < 4; ++j) acc[i][j] = (f32x4){0.f, 0.f, 0.f, 0.f};
  gemm_tb((const char*)(X + (long)tm * D_), D_ * 2,
          (const char*)(Wsel + (long)tnl * D_), D_ * 2, D_ / 64, lds, acc);
  const int tid = threadIdx.x;
  const int lane = tid & 63, wave = tid >> 6;
  const int wm = wave >> 1, wn = wave & 1;
  const int quad = lane >> 4, l16 = lane & 15;
  if (w < 2) {
    const float* bias = w ? bk : bq;
    f16* outp = w ? Ko : Q;
#pragma unroll
    for (int j = 0; j < 4; ++j) {
      int col = tnl + wn * 64 + j * 16 + l16;
      float bb = bias[col];
#pragma unroll
      for (int i = 0; i < 4; ++i) {
        int rbase = tm + wm * 64 + i * 16 + quad * 4;
#pragma unroll
        for (int r = 0; r < 4; ++r)
          outp[(long)(rbase + r) * D_ + col] = (_Float16)(acc[i][j][r] + bb);
      }
    }
  } else {
    // V: transpose through LDS (128 features x 264-f16 pitch), write Vt coalesced
    int bidx = tm >> 11, ntok = tm & 2047;
    f16* VtB = Vt + (long)bidx * D_ * N_ + ntok;
    f16* ldsT = (f16*)lds;
#pragma unroll
    for (int j = 0; j < 4; ++j) {
      int cl = wn * 64 + j * 16 + l16;        // local feature 0..127
      float bb = bv[tnl + cl];
#pragma unroll
      for (int i = 0; i < 4; ++i) {
        int rl = wm * 64 + i * 16 + quad * 4; // local token 0..255
        f16x4 p = { (_Float16)(acc[i][j][0] + bb), (_Float16)(acc[i][j][1] + bb),
                    (_Float16)(acc[i][j][2] + bb), (_Float16)(acc[i][j][3] + bb) };
        *(f16x4*)(ldsT + cl * 264 + rl) = p;
      }
    }
    FENCE;
    __builtin_amdgcn_s_barrier();
    FENCE;
#pragma unroll
    for (int p = 0; p < 8; ++p) {
      int f = p * 16 + (tid >> 5);            // 0..127
      int cc = tid & 31;                      // 32 x 8 f16 = 256 tokens
      f16x8 v = *(const f16x8*)(ldsT + f * 264 + cc * 8);
      *(f16x8*)(VtB + (long)(tnl + f) * N_ + cc * 8) = v;
    }
  }
}

// ---------------------------------------------------------------- scores: P' = exp(QK^T*delta)
// 256x256 tile, 256 blocks (exactly 1/CU). 2-pass LDS bounce for coalesced stores.
__global__ __launch_bounds__(512, 2) void k_scores(const f16* __restrict__ Qf,
                                                   const f16* __restrict__ Kf,
                                                   f16* __restrict__ S,
                                                   float* __restrict__ rowsum) {
  __shared__ __align__(16) char lds[131072];
  int fid = blockIdx.x;
  int xcd = fid & 7, k = fid >> 3;
  int lin = xcd * 32 + k;
  int b = lin >> 6;
  int t = lin & 63;
  int rowt = t & 7, colt = t >> 3;
  int tm = rowt * 256, tn = colt * 256;
  f32x4 acc[2][4][2][2];
#pragma unroll
  for (int Ah = 0; Ah < 2; ++Ah)
#pragma unroll
    for (int i = 0; i < 4; ++i)
#pragma unroll
      for (int Bh = 0; Bh < 2; ++Bh)
#pragma unroll
        for (int jn = 0; jn < 2; ++jn) acc[Ah][i][Bh][jn] = (f32x4){0.f, 0.f, 0.f, 0.f};
  gemm256((const char*)(Qf + (long)b * N_ * D_ + (long)tm * D_), D_ * 2,
          (const char*)(Kf + (long)b * N_ * D_ + (long)tn * D_), D_ * 2,
          D_ / 64, lds, acc);
  const int tid = threadIdx.x;
  const int lane = tid & 63, wave = tid >> 6;
  const int wm = wave >> 2, wn = wave & 3;
  const int quad = lane >> 4, l16 = lane & 15;
  f16* Sb = S + (long)b * N_ * N_;
  const float delta = 0.03125f;               // 1/sqrt(1024); exp <= ~e^6, f16-safe
  f16* ldsS = (f16*)lds;                      // 256 x 136 f16 per pass
  float rsum[2][4][4];
#pragma unroll
  for (int Ah = 0; Ah < 2; ++Ah)
#pragma unroll
    for (int i = 0; i < 4; ++i)
#pragma unroll
      for (int r = 0; r < 4; ++r) rsum[Ah][i][r] = 0.f;
#pragma unroll
  for (int Bh = 0; Bh < 2; ++Bh) {            // pass over col-halves
    FENCE;
    __builtin_amdgcn_s_barrier();
    FENCE;
#pragma unroll
    for (int Ah = 0; Ah < 2; ++Ah)
#pragma unroll
      for (int i = 0; i < 4; ++i) {
        int rloc = Ah * 128 + wm * 64 + i * 16 + quad * 4;
#pragma unroll
        for (int jn = 0; jn < 2; ++jn) {
          int col = wn * 32 + jn * 16 + l16;
#pragma unroll
          for (int r = 0; r < 4; ++r) {
            float e = __expf(acc[Ah][i][Bh][jn][r] * delta);
            rsum[Ah][i][r] += e;
            ldsS[(rloc + r) * 136 + col] = (_Float16)e;
          }
        }
      }
    FENCE;
    __builtin_amdgcn_s_barrier();
    FENCE;
#pragma unroll
    for (int p = 0; p < 8; ++p) {
      int row = p * 32 + (tid >> 4);
      int cc = tid & 15;
      f16x8 v = *(const f16x8*)(ldsS + row * 136 + cc * 8);
      *(f16x8*)(Sb + (long)(tm + row) * N_ + tn + Bh * 128 + cc * 8) = v;
    }
  }
#pragma unroll
  for (int m = 1; m < 16; m <<= 1)
#pragma unroll
    for (int Ah = 0; Ah < 2; ++Ah)
#pragma unroll
      for (int i = 0; i < 4; ++i)
#pragma unroll
        for (int r = 0; r < 4; ++r) rsum[Ah][i][r] += __shfl_xor(rsum[Ah][i][r], m);
  if (l16 == 0) {
    float* rs = rowsum + (long)b * N_ + tm;
#pragma unroll
    for (int Ah = 0; Ah < 2; ++Ah)
#pragma unroll
      for (int i = 0; i < 4; ++i)
#pragma unroll
        for (int r = 0; r < 4; ++r)
          atomicAdd(rs + Ah * 128 + wm * 64 + i * 16 + quad * 4 + r, rsum[Ah][i][r]);
  }
}

// ---------------------------------------------------------------- O = (P' V)/rowsum * gamma + x
// 256x128 tiles -> 64/batch, 256 blocks exactly. K = 2048 (32 K-tiles, deep pipeline).
__global__ __launch_bounds__(512, 2) void k_out(const f16* __restrict__ P,
                                                const f16* __restrict__ Vt,
                                                const f16* __restrict__ xf,
                                                const float* __restrict__ gamma,
                                                const float* __restrict__ rowsum,
                                                float* __restrict__ out) {
  __shared__ __align__(16) char lds[147456];
  int fid = blockIdx.x;
  int xcd = fid & 7, kq = fid >> 3;
  int lin = xcd * 32 + kq;
  int b = lin >> 6;
  int t = lin & 63;
  int rowt = t >> 3, colt = t & 7;          // colt fast: P row-panel L2-reused across 8 blocks
  int tm = rowt * 256, tn = colt * 128;
  f32x4 acc[4][4];
#pragma unroll
  for (int i = 0; i < 4; ++i)
#pragma unroll
    for (int j = 0; j < 4; ++j) acc[i][j] = (f32x4){0.f, 0.f, 0.f, 0.f};
  gemm_tb((const char*)(P + (long)b * N_ * N_ + (long)tm * N_), N_ * 2,
          (const char*)(Vt + (long)b * D_ * N_ + (long)tn * N_), N_ * 2,
          N_ / 64, lds, acc);
  const int tid = threadIdx.x;
  const int lane = tid & 63, wave = tid >> 6;
  const int wm = wave >> 1, wn = wave & 1;
  const int quad = lane >> 4, l16 = lane & 15;
  float g = gamma[0];
  float inv[4][4];
#pragma unroll
  for (int i = 0; i < 4; ++i)
#pragma unroll
    for (int r = 0; r < 4; ++r)
      inv[i][r] = g / rowsum[(long)b * N_ + tm + wm * 64 + i * 16 + quad * 4 + r];
#pragma unroll
  for (int j = 0; j < 4; ++j) {
    int col = tn + wn * 64 + j * 16 + l16;
#pragma unroll
    for (int i = 0; i < 4; ++i) {
      int rbase = tm + wm * 64 + i * 16 + quad * 4;
#pragma unroll
      for (int r = 0; r < 4; ++r) {
        long idx = (long)b * N_ * D_ + (long)(rbase + r) * D_ + col;
        out[idx] = acc[i][j][r] * inv[i][r] + (float)xf[idx];
      }
    }
  }
}

// ---------------------------------------------------------------- launch
extern "C" void kernel_launch(void* const* d_in, const int* in_sizes, int n_in,
                              void* d_out, int out_size, void* d_ws, size_t ws_size,
                              hipStream_t stream) {
  const float* x  = (const float*)d_in[0];
  const float* Wq = (const float*)d_in[1];
  const float* bq = (const float*)d_in[2];
  const float* Wk = (const float*)d_in[3];
  const float* bk = (const float*)d_in[4];
  const float* Wv = (const float*)d_in[5];
  const float* bv = (const float*)d_in[6];
  const float* gamma = (const float*)d_in[7];
  float* out = (float*)d_out;
  char* ws = (char*)d_ws;

  // ws layout: Xb stays ALIVE through k_out (x re-read as f16).
  // S overlays only the dead W buffers. Peak 96 MB (+32 KB rowsum).
  f16* Qb  = (f16*)(ws);                      // 0..16 MB
  f16* Kb  = (f16*)(ws + (16u << 20));        // 16..32 MB
  f16* Vt  = (f16*)(ws + (32u << 20));        // 32..48 MB (written directly by k_qkv)
  f16* Xb  = (f16*)(ws + (48u << 20));        // 48..64 MB (alive through k_out)
  f16* Wqb = (f16*)(ws + (64u << 20));        // 64..66 MB (dead after k_qkv)
  f16* Wkb = (f16*)(ws + (66u << 20));        // 66..68 MB
  f16* Wvb = (f16*)(ws + (68u << 20));        // 68..70 MB
  f16* S   = (f16*)(ws + (64u << 20));        // 64..96 MB, overlays dead W's
  float* rowsum = (float*)(ws + (96u << 20)); // 32 KB

  k_cast_all<<<11296, 256, 0, stream>>>((const float4*)x, (const float4*)Wq,
                                        (const float4*)Wk, (const float4*)Wv,
                                        (f16x4*)Xb, (f16x4*)Wqb, (f16x4*)Wkb, (f16x4*)Wvb,
                                        rowsum);
  k_qkv<<<768, 512, 0, stream>>>(Xb, Wqb, Wkb, Wvb, bq, bk, bv, Qb, Kb, Vt);
  k_scores<<<256, 512, 0, stream>>>(Qb, Kb, S, rowsum);
  k_out<<<256, 512, 0, stream>>>(S, Vt, Xb, gamma, rowsum, out);
}